// Round 7
// baseline (631.769 us; speedup 1.0000x reference)
//
#include <hip/hip_runtime.h>
#include <math.h>

#define NUM_TOKENS 16384
#define HD 4096
#define HD4 (HD / 4)          // 1024 float4 per row
#define NE 8

#define BLOCK_THREADS 1024
#define WAVES_PER_BLOCK 16
#define TOK_PER_WAVE 2        // 2 tokens/wave -> acc 16 regs, bufs 32 regs (~60 live, fits 64-VGPR budget)
#define CHUNKS 2              // each block does 2 token-chunks, reusing staged gate
#define TOK_PER_CHUNK (WAVES_PER_BLOCK * TOK_PER_WAVE)          // 32
#define NUM_BLOCKS (NUM_TOKENS / (CHUNKS * TOK_PER_CHUNK))      // 256
#define KITERS (HD4 / 64)                                        // 16

typedef float vfloat4 __attribute__((ext_vector_type(4)));

// One block per CU (128 KB LDS gate stage). 4-deep rotating prefetch.
// R6 lesson: launch_bounds(.,4) did NOT raise the 64-VGPR allocator budget
// (still 825 MB spill traffic). Two fixes: (a) working set trimmed to ~60
// regs so even a 64-reg budget has no spills; (b) amdgpu_waves_per_eu(4,4)
// as the direct backend knob (LDS caps us at 4 waves/EU anyway).
__global__ __launch_bounds__(BLOCK_THREADS)
__attribute__((amdgpu_waves_per_eu(4, 4)))
void router_kernel(const float* __restrict__ hidden,
                   const float* __restrict__ gate,
                   float* __restrict__ out_w,    // [T,2]
                   float* __restrict__ out_idx,  // [T,2] stored as float
                   float* __restrict__ partial)  // [NUM_BLOCKS][16] in ws
{
    __shared__ vfloat4 g_lds[NE * HD4];   // 128 KB
    __shared__ float   s_acc[16];

    const int tid = threadIdx.x;

    // Stage gate weight into LDS (coalesced float4 copy).
    const vfloat4* g4 = (const vfloat4*)gate;
    #pragma unroll
    for (int i = 0; i < (NE * HD4) / BLOCK_THREADS; ++i)
        g_lds[tid + i * BLOCK_THREADS] = g4[tid + i * BLOCK_THREADS];
    if (tid < 16) s_acc[tid] = 0.0f;
    __syncthreads();

    const int wave = tid >> 6;
    const int lane = tid & 63;
    const vfloat4* h4 = (const vfloat4*)hidden;

    #pragma unroll 1
    for (int c = 0; c < CHUNKS; ++c) {
        const int tokBase =
            ((c * NUM_BLOCKS + blockIdx.x) * WAVES_PER_BLOCK + wave) * TOK_PER_WAVE;
        const size_t rowBase = (size_t)tokBase * HD4 + lane;

        float acc[TOK_PER_WAVE][NE];
        #pragma unroll
        for (int t = 0; t < TOK_PER_WAVE; ++t)
            #pragma unroll
            for (int e = 0; e < NE; ++e) acc[t][e] = 0.0f;

        vfloat4 bufA[TOK_PER_WAVE], bufB[TOK_PER_WAVE];
        vfloat4 bufC[TOK_PER_WAVE], bufD[TOK_PER_WAVE];

#define LOADBUF(BUF, KK)                                                     \
    {                                                                        \
        const size_t _o = rowBase + (size_t)(KK) * 64;                       \
        _Pragma("unroll")                                                    \
        for (int t = 0; t < TOK_PER_WAVE; ++t)                               \
            BUF[t] = __builtin_nontemporal_load(&h4[_o + (size_t)t * HD4]); \
    }

#define PHASE(BUF, KK)                                                       \
    {                                                                        \
        const int _d4 = lane + (KK) * 64;                                    \
        _Pragma("unroll")                                                    \
        for (int e = 0; e < NE; ++e) {                                       \
            const vfloat4 g = g_lds[e * HD4 + _d4];                          \
            _Pragma("unroll")                                                \
            for (int t = 0; t < TOK_PER_WAVE; ++t)                           \
                acc[t][e] += BUF[t].x * g.x + BUF[t].y * g.y                 \
                           + BUF[t].z * g.z + BUF[t].w * g.w;                \
        }                                                                    \
    }

        LOADBUF(bufA, 0)
        LOADBUF(bufB, 1)
        LOADBUF(bufC, 2)
        LOADBUF(bufD, 3)

        #pragma unroll 1
        for (int k = 0; k < KITERS; k += 4) {
            PHASE(bufA, k)
            if (k + 4 < KITERS) LOADBUF(bufA, k + 4)
            PHASE(bufB, k + 1)
            if (k + 5 < KITERS) LOADBUF(bufB, k + 5)
            PHASE(bufC, k + 2)
            if (k + 6 < KITERS) LOADBUF(bufC, k + 6)
            PHASE(bufD, k + 3)
            if (k + 7 < KITERS) LOADBUF(bufD, k + 7)
        }
#undef LOADBUF
#undef PHASE

        // Butterfly reduce the 16 partials across the 64-lane wave.
        #pragma unroll
        for (int t = 0; t < TOK_PER_WAVE; ++t)
            #pragma unroll
            for (int e = 0; e < NE; ++e) {
                float v = acc[t][e];
                #pragma unroll
                for (int off = 32; off >= 1; off >>= 1)
                    v += __shfl_xor(v, off, 64);
                acc[t][e] = v;
            }

        // Lanes 0..1: epilogue for token tokBase+lane.
        if (lane < TOK_PER_WAVE) {
            const int tok = tokBase + lane;
            float p[NE];
            float m = acc[lane][0];
            #pragma unroll
            for (int e = 1; e < NE; ++e) m = fmaxf(m, acc[lane][e]);
            float s = 0.0f;
            #pragma unroll
            for (int e = 0; e < NE; ++e) { p[e] = expf(acc[lane][e] - m); s += p[e]; }
            const float inv = 1.0f / s;
            #pragma unroll
            for (int e = 0; e < NE; ++e) p[e] *= inv;

            // top-2, ties -> lowest index (matches jax.lax.top_k)
            int i1 = 0;
            #pragma unroll
            for (int e = 1; e < NE; ++e) if (p[e] > p[i1]) i1 = e;
            int i2 = (i1 == 0) ? 1 : 0;
            #pragma unroll
            for (int e = 0; e < NE; ++e) if (e != i1 && p[e] > p[i2]) i2 = e;

            const float w1 = p[i1], w2 = p[i2];
            const float rs = 1.0f / (w1 + w2);
            float2 wv = make_float2(w1 * rs, w2 * rs);
            float2 iv = make_float2((float)i1, (float)i2);
            *(float2*)&out_w[tok * 2]   = wv;
            *(float2*)&out_idx[tok * 2] = iv;

            atomicAdd(&s_acc[i1], 1.0f);
            atomicAdd(&s_acc[i2], 1.0f);
            #pragma unroll
            for (int e = 0; e < NE; ++e) atomicAdd(&s_acc[8 + e], p[e]);
        }
    }

    __syncthreads();
    // Per-block partials: plain stores (poison-safe, no zero-init needed).
    if (tid < 16) partial[blockIdx.x * 16 + tid] = s_acc[tid];
}

// Reduce 256x16 partials -> aux loss. One block, 256 threads (4 waves).
__global__ void finalize_kernel(const float* __restrict__ partial,
                                float* __restrict__ aux_out)
{
    __shared__ float s_acc[16];
    const int tid = threadIdx.x;            // 0..255 (one slot per router block)
    if (tid < 16) s_acc[tid] = 0.0f;
    __syncthreads();

    float p[16];
    const vfloat4* p4 = (const vfloat4*)(partial + (size_t)tid * 16);
    #pragma unroll
    for (int i = 0; i < 4; ++i) {
        vfloat4 v = p4[i];
        p[4 * i + 0] = v.x; p[4 * i + 1] = v.y;
        p[4 * i + 2] = v.z; p[4 * i + 3] = v.w;
    }
    #pragma unroll
    for (int j = 0; j < 16; ++j) {
        #pragma unroll
        for (int off = 32; off >= 1; off >>= 1)
            p[j] += __shfl_xor(p[j], off, 64);
    }
    if ((tid & 63) == 0) {
        #pragma unroll
        for (int j = 0; j < 16; ++j) atomicAdd(&s_acc[j], p[j]);
    }
    __syncthreads();
    if (tid == 0) {
        const float invT = 1.0f / (float)NUM_TOKENS;
        float s = 0.0f;
        #pragma unroll
        for (int e = 0; e < NE; ++e)
            s += (s_acc[e] * invT) * (s_acc[8 + e] * invT);
        aux_out[0] = (float)NE * s;
    }
}

extern "C" void kernel_launch(void* const* d_in, const int* in_sizes, int n_in,
                              void* d_out, int out_size, void* d_ws, size_t ws_size,
                              hipStream_t stream) {
    const float* hidden = (const float*)d_in[0];   // [16384, 4096] f32
    const float* gate   = (const float*)d_in[1];   // [8, 4096] f32
    float* out = (float*)d_out;
    float* out_w   = out;                       // 16384*2
    float* out_idx = out + NUM_TOKENS * 2;      // 16384*2
    float* aux     = out + NUM_TOKENS * 4;      // 1
    float* partial = (float*)d_ws;              // 256*16 floats

    router_kernel<<<NUM_BLOCKS, BLOCK_THREADS, 0, stream>>>(hidden, gate, out_w, out_idx, partial);
    finalize_kernel<<<1, 256, 0, stream>>>(partial, aux);
}

// Round 8
// 379.180 us; speedup vs baseline: 1.6661x; 1.6661x over previous
//
#include <hip/hip_runtime.h>
#include <math.h>

#define NUM_TOKENS 16384
#define HD 4096
#define HD4 (HD / 4)          // 1024 float4 per row
#define NE 8

#define BLOCK_THREADS 1024
#define WAVES_PER_BLOCK 16
#define TOK_PER_WAVE 2        // acc 16 regs; 2 ping-pong bufs 16 regs (~50 live)
#define CHUNKS 2              // each block does 2 token-chunks, reusing staged gate
#define TOK_PER_CHUNK (WAVES_PER_BLOCK * TOK_PER_WAVE)          // 32
#define NUM_BLOCKS (NUM_TOKENS / (CHUNKS * TOK_PER_CHUNK))      // 256
#define KITERS (HD4 / 64)                                        // 16

typedef float vfloat4 __attribute__((ext_vector_type(4)));

// One block per CU (128 KB LDS gate stage). Depth-2 ping-pong prefetch.
// R7 lesson: 840 MB of phantom HBM writes persisted after shrinking the
// register working set -> NOT classic spills. Prime suspect: the `nt`
// (nontemporal) cache policy on the hidden-state stream. This round: plain
// loads (no nt), branch-free clamped prefetch offsets, ~50 live VGPRs.
__global__ __launch_bounds__(BLOCK_THREADS)
void router_kernel(const float* __restrict__ hidden,
                   const float* __restrict__ gate,
                   float* __restrict__ out_w,    // [T,2]
                   float* __restrict__ out_idx,  // [T,2] stored as float
                   float* __restrict__ partial)  // [NUM_BLOCKS][16] in ws
{
    __shared__ vfloat4 g_lds[NE * HD4];   // 128 KB
    __shared__ float   s_acc[16];

    const int tid = threadIdx.x;

    // Stage gate weight into LDS (coalesced float4 copy).
    const vfloat4* g4 = (const vfloat4*)gate;
    #pragma unroll
    for (int i = 0; i < (NE * HD4) / BLOCK_THREADS; ++i)
        g_lds[tid + i * BLOCK_THREADS] = g4[tid + i * BLOCK_THREADS];
    if (tid < 16) s_acc[tid] = 0.0f;
    __syncthreads();

    const int wave = tid >> 6;
    const int lane = tid & 63;
    const vfloat4* h4 = (const vfloat4*)hidden;

    #pragma unroll 1
    for (int c = 0; c < CHUNKS; ++c) {
        const int tokBase =
            ((c * NUM_BLOCKS + blockIdx.x) * WAVES_PER_BLOCK + wave) * TOK_PER_WAVE;
        const size_t rowBase = (size_t)tokBase * HD4 + lane;

        float acc[TOK_PER_WAVE][NE];
        #pragma unroll
        for (int t = 0; t < TOK_PER_WAVE; ++t)
            #pragma unroll
            for (int e = 0; e < NE; ++e) acc[t][e] = 0.0f;

        vfloat4 bufA[TOK_PER_WAVE], bufB[TOK_PER_WAVE];

#define LOADBUF(BUF, KK)                                                     \
    {                                                                        \
        const size_t _o = rowBase + (size_t)(KK) * 64;                       \
        _Pragma("unroll")                                                    \
        for (int t = 0; t < TOK_PER_WAVE; ++t)                               \
            BUF[t] = h4[_o + (size_t)t * HD4];                               \
    }

#define PHASE(BUF, KK)                                                       \
    {                                                                        \
        const int _d4 = lane + (KK) * 64;                                    \
        _Pragma("unroll")                                                    \
        for (int e = 0; e < NE; ++e) {                                       \
            const vfloat4 g = g_lds[e * HD4 + _d4];                          \
            _Pragma("unroll")                                                \
            for (int t = 0; t < TOK_PER_WAVE; ++t)                           \
                acc[t][e] += BUF[t].x * g.x + BUF[t].y * g.y                 \
                           + BUF[t].z * g.z + BUF[t].w * g.w;                \
        }                                                                    \
    }

        LOADBUF(bufA, 0)
        LOADBUF(bufB, 1)

        #pragma unroll 1
        for (int k = 0; k < KITERS; k += 2) {
            // Branch-free clamped prefetch offsets (tail re-loads an already
            // consumed tile; values unused, cost negligible, code stays linear).
            const int ka = (k + 2 < KITERS) ? (k + 2) : k;
            const int kb = (k + 3 < KITERS) ? (k + 3) : (k + 1);
            PHASE(bufA, k)
            LOADBUF(bufA, ka)
            PHASE(bufB, k + 1)
            LOADBUF(bufB, kb)
        }
#undef LOADBUF
#undef PHASE

        // Butterfly reduce the 16 partials across the 64-lane wave.
        #pragma unroll
        for (int t = 0; t < TOK_PER_WAVE; ++t)
            #pragma unroll
            for (int e = 0; e < NE; ++e) {
                float v = acc[t][e];
                #pragma unroll
                for (int off = 32; off >= 1; off >>= 1)
                    v += __shfl_xor(v, off, 64);
                acc[t][e] = v;
            }

        // Lanes 0..1: epilogue for token tokBase+lane.
        if (lane < TOK_PER_WAVE) {
            const int tok = tokBase + lane;
            float p[NE];
            float m = acc[lane][0];
            #pragma unroll
            for (int e = 1; e < NE; ++e) m = fmaxf(m, acc[lane][e]);
            float s = 0.0f;
            #pragma unroll
            for (int e = 0; e < NE; ++e) { p[e] = expf(acc[lane][e] - m); s += p[e]; }
            const float inv = 1.0f / s;
            #pragma unroll
            for (int e = 0; e < NE; ++e) p[e] *= inv;

            // top-2, ties -> lowest index (matches jax.lax.top_k)
            int i1 = 0;
            #pragma unroll
            for (int e = 1; e < NE; ++e) if (p[e] > p[i1]) i1 = e;
            int i2 = (i1 == 0) ? 1 : 0;
            #pragma unroll
            for (int e = 0; e < NE; ++e) if (e != i1 && p[e] > p[i2]) i2 = e;

            const float w1 = p[i1], w2 = p[i2];
            const float rs = 1.0f / (w1 + w2);
            float2 wv = make_float2(w1 * rs, w2 * rs);
            float2 iv = make_float2((float)i1, (float)i2);
            *(float2*)&out_w[tok * 2]   = wv;
            *(float2*)&out_idx[tok * 2] = iv;

            atomicAdd(&s_acc[i1], 1.0f);
            atomicAdd(&s_acc[i2], 1.0f);
            #pragma unroll
            for (int e = 0; e < NE; ++e) atomicAdd(&s_acc[8 + e], p[e]);
        }
    }

    __syncthreads();
    // Per-block partials: plain stores (poison-safe, no zero-init needed).
    if (tid < 16) partial[blockIdx.x * 16 + tid] = s_acc[tid];
}

// Reduce 256x16 partials -> aux loss. One block, 256 threads (4 waves).
__global__ void finalize_kernel(const float* __restrict__ partial,
                                float* __restrict__ aux_out)
{
    __shared__ float s_acc[16];
    const int tid = threadIdx.x;            // 0..255 (one slot per router block)
    if (tid < 16) s_acc[tid] = 0.0f;
    __syncthreads();

    float p[16];
    const vfloat4* p4 = (const vfloat4*)(partial + (size_t)tid * 16);
    #pragma unroll
    for (int i = 0; i < 4; ++i) {
        vfloat4 v = p4[i];
        p[4 * i + 0] = v.x; p[4 * i + 1] = v.y;
        p[4 * i + 2] = v.z; p[4 * i + 3] = v.w;
    }
    #pragma unroll
    for (int j = 0; j < 16; ++j) {
        #pragma unroll
        for (int off = 32; off >= 1; off >>= 1)
            p[j] += __shfl_xor(p[j], off, 64);
    }
    if ((tid & 63) == 0) {
        #pragma unroll
        for (int j = 0; j < 16; ++j) atomicAdd(&s_acc[j], p[j]);
    }
    __syncthreads();
    if (tid == 0) {
        const float invT = 1.0f / (float)NUM_TOKENS;
        float s = 0.0f;
        #pragma unroll
        for (int e = 0; e < NE; ++e)
            s += (s_acc[e] * invT) * (s_acc[8 + e] * invT);
        aux_out[0] = (float)NE * s;
    }
}

extern "C" void kernel_launch(void* const* d_in, const int* in_sizes, int n_in,
                              void* d_out, int out_size, void* d_ws, size_t ws_size,
                              hipStream_t stream) {
    const float* hidden = (const float*)d_in[0];   // [16384, 4096] f32
    const float* gate   = (const float*)d_in[1];   // [8, 4096] f32
    float* out = (float*)d_out;
    float* out_w   = out;                       // 16384*2
    float* out_idx = out + NUM_TOKENS * 2;      // 16384*2
    float* aux     = out + NUM_TOKENS * 4;      // 1
    float* partial = (float*)d_ws;              // 256*16 floats

    router_kernel<<<NUM_BLOCKS, BLOCK_THREADS, 0, stream>>>(hidden, gate, out_w, out_idx, partial);
    finalize_kernel<<<1, 256, 0, stream>>>(partial, aux);
}